// Round 13
// baseline (221.274 us; speedup 1.0000x reference)
//
#include <hip/hip_runtime.h>

// ArcMarginLoss fused: normalize -> MX-fp8 MFMA GEMM + fixed-max softmax -> NLL mean.
// N=8192, D=512, C=32000, scale=16, margin=0.2.
// R13: hypothesis test on the ~400cyc/chunk unattributed wait (4 rounds pinned at
// MfmaUtil~51%). Dual B buffers with prefetch lead of 2 chunks (~2200cyc; also
// removes the WAR hazard of refilling b[ks] right after MFMAs that read it) +
// R10's acc ping-pong exp interleave + s_setprio(1) around each 4-MFMA burst
// (waves drift freely -> role diversity -> T5 applies). VGPR ~250 (2 waves/SIMD).
// Spill tripwire: hbm_bytes >> 100MB => revert.

typedef __attribute__((ext_vector_type(4))) float f32x4;
typedef __attribute__((ext_vector_type(8))) int i32x8;

constexpr int N = 8192, D = 512, C = 32000;
constexpr int BM = 256;            // rows per block (4 waves x 4 tiles x 16 rows)
constexpr int GRP = 16;            // cols per chunk
constexpr int NSPLIT = 16;         // column splits of C
constexpr int CPS = C / NSPLIT;    // 2000 cols per split
constexpr int NCHUNK = CPS / GRP;  // 125 chunks
constexpr int KS = D / 128;        // 4 k-steps of K=128
constexpr float SCL = 16.0f;
constexpr float LOG2E = 1.4426950408889634f;
constexpr float COSM = 0.98006657784124163f;  // cos(0.2)
constexpr float SINM = 0.19866933079506122f;  // sin(0.2)
constexpr float EPSC = 1e-7f;
constexpr float EM16 = 1.12535174719259114e-07f;  // exp(-16)
constexpr int SCQ = 0x81818181;    // E8M0 byte 129 -> 2^2 per operand (2^4 total)
// Schraudolph zero-mean fast exp2: 2^y ~= bitcast_f32((uint)(y*2^23 + FEC)).
constexpr float FEC = 1064871712.0f;

// Pack 8 scaled floats -> 8 fp8 e4m3 bytes (two i32 words), hw RNE+sat.
__device__ __forceinline__ void pack8_fp8(const float* f, float sc, int& lo, int& hi) {
  lo = __builtin_amdgcn_cvt_pk_fp8_f32(f[0] * sc, f[1] * sc, 0, 0);
  lo = __builtin_amdgcn_cvt_pk_fp8_f32(f[2] * sc, f[3] * sc, lo, 1);
  hi = __builtin_amdgcn_cvt_pk_fp8_f32(f[4] * sc, f[5] * sc, 0, 0);
  hi = __builtin_amdgcn_cvt_pk_fp8_f32(f[6] * sc, f[7] * sc, hi, 1);
}

// x: one wave per row, L2-normalize, scale by log2e (MX scale supplies 2^4),
// emit row-major fp8 (8 B/lane). Also zero-inits the output scalar (block 0).
__global__ void k_norm_x(const float* __restrict__ in, char* __restrict__ out,
                         float* __restrict__ outz) {
  if (blockIdx.x == 0 && threadIdx.x == 0) *outz = 0.0f;
  int w = (blockIdx.x << 2) + (threadIdx.x >> 6);
  int lane = threadIdx.x & 63;
  const float* row = in + (size_t)w * D;
  float f[8];
  *(f32x4*)&f[0] = *(const f32x4*)(row + lane * 8);
  *(f32x4*)&f[4] = *(const f32x4*)(row + lane * 8 + 4);
  float ss = 0.f;
  #pragma unroll
  for (int i = 0; i < 8; ++i) ss += f[i] * f[i];
  #pragma unroll
  for (int m = 1; m <= 32; m <<= 1) ss += __shfl_xor(ss, m, 64);
  float sc = LOG2E / fmaxf(sqrtf(ss), 1e-12f);
  int lo, hi;
  pack8_fp8(f, sc, lo, hi);
  int2 pk; pk.x = lo; pk.y = hi;
  *(int2*)(out + (size_t)w * D + lane * 8) = pk;
}

// w: one block per 16-col group; normalize 16 rows, emit fused-ready layout.
// Per 8KB group: byte addr = ks*2048 + (g*16 + col)*32 + j holds
// w[col][ks*128 + g*32 + j] (j in 0..31): each fused lane's 32B is contiguous.
__global__ void k_normw_t(const float* __restrict__ in, char* __restrict__ wt) {
  __shared__ __align__(16) char lbuf[8192];
  const int tid = threadIdx.x, wv = tid >> 6, L = tid & 63;
  const int gidx = blockIdx.x;
  #pragma unroll
  for (int t = 0; t < 4; ++t) {
    int rl = t * 4 + wv;  // 0..15 (col within group)
    const float* row = in + ((size_t)gidx * 16 + rl) * D;
    float f[8];
    *(f32x4*)&f[0] = *(const f32x4*)(row + L * 8);
    *(f32x4*)&f[4] = *(const f32x4*)(row + L * 8 + 4);
    float ss = 0.f;
    #pragma unroll
    for (int i = 0; i < 8; ++i) ss += f[i] * f[i];
    #pragma unroll
    for (int m = 1; m <= 32; m <<= 1) ss += __shfl_xor(ss, m, 64);
    float sc = 1.0f / fmaxf(sqrtf(ss), 1e-12f);
    int lo, hi;
    pack8_fp8(f, sc, lo, hi);
    // lane L covers k in [8L,8L+8): ks=L>>4, g=(L>>2)&3, j0=(L&3)*8
    int addr = (L >> 4) * 2048 + (((L >> 2) & 3) * 16 + rl) * 32 + (L & 3) * 8;
    long pk = ((long)(unsigned)hi << 32) | (unsigned)lo;
    *(long*)(lbuf + addr) = pk;
  }
  __syncthreads();
  char* outp = wt + (size_t)gidx * 8192;
  #pragma unroll
  for (int i = 0; i < 2; ++i)
    *(uint4*)(outp + i * 4096 + tid * 16) = *(const uint4*)(lbuf + i * 4096 + tid * 16);
}

// Label-column cosine in f32 (one wave per row) -> coslab[N].
__global__ void k_lab(const float* __restrict__ x, const float* __restrict__ w,
                      const int* __restrict__ labels, float* __restrict__ coslab) {
  int r = (blockIdx.x << 2) + (threadIdx.x >> 6);
  int lane = threadIdx.x & 63;
  const float* xr = x + (size_t)r * D;
  const float* wr = w + (size_t)labels[r] * D;
  f32x4 a = *(const f32x4*)(xr + lane * 8);
  f32x4 b = *(const f32x4*)(xr + lane * 8 + 4);
  f32x4 p = *(const f32x4*)(wr + lane * 8);
  f32x4 q = *(const f32x4*)(wr + lane * 8 + 4);
  float xx = a.x*a.x + a.y*a.y + a.z*a.z + a.w*a.w + b.x*b.x + b.y*b.y + b.z*b.z + b.w*b.w;
  float ww = p.x*p.x + p.y*p.y + p.z*p.z + p.w*p.w + q.x*q.x + q.y*q.y + q.z*q.z + q.w*q.w;
  float xw = a.x*p.x + a.y*p.y + a.z*p.z + a.w*p.w + b.x*q.x + b.y*q.y + b.z*q.z + b.w*q.w;
  #pragma unroll
  for (int m = 1; m <= 32; m <<= 1) {
    xx += __shfl_xor(xx, m, 64);
    ww += __shfl_xor(ww, m, 64);
    xw += __shfl_xor(xw, m, 64);
  }
  if (lane == 0)
    coslab[r] = xw / (fmaxf(sqrtf(xx), 1e-12f) * fmaxf(sqrtf(ww), 1e-12f));
}

// One chunk against BUF: 4 bursts of 4 MFMAs (setprio-wrapped), fast-exp2
// epilogue of ACCPREV interleaved, BUF refilled from absolute chunk CN
// (2 chunks ahead -> ~2200cyc prefetch lead, no WAR on in-flight operands).
#define CHUNK_STEP(ACC, ACCPREV, BUF, DOEXP, CN)                              \
  {                                                                           \
    _Pragma("unroll")                                                         \
    for (int ks = 0; ks < KS; ++ks) {                                         \
      __builtin_amdgcn_s_setprio(1);                                          \
      _Pragma("unroll")                                                       \
      for (int t = 0; t < 4; ++t)                                             \
        ACC[t] = __builtin_amdgcn_mfma_scale_f32_16x16x128_f8f6f4(            \
            af[t][ks], BUF[ks], ks == 0 ? fzero : ACC[t], 0, 0, 0,            \
            SCQ, 0, SCQ);                                                     \
      __builtin_amdgcn_s_setprio(0);                                          \
      if (DOEXP) {                                                            \
        _Pragma("unroll")                                                     \
        for (int r = 0; r < 4; ++r)                                           \
          accS[ks][r] += __uint_as_float(                                     \
              (unsigned)fmaf(ACCPREV[ks][r], 8388608.0f, FEC));               \
      }                                                                       \
      BUF[ks] = *(const i32x8*)(gb + (size_t)(CN) * 8192 + ks * 2048);        \
    }                                                                         \
  }

// Fused MX-fp8 GEMM, barrier-free, dual-buffer depth-2 prefetch + acc ping-pong.
__global__ __launch_bounds__(256, 2) void k_fused(
    const char* __restrict__ xn8, const char* __restrict__ wt,
    float* __restrict__ pS) {
  const int tid = threadIdx.x;
  const int wv = tid >> 6, lane = tid & 63;
  const int g = lane >> 4, c = lane & 15;
  const int bid = blockIdx.x;
  const int logical = (bid & 7) * 64 + (bid >> 3);  // 512 = 8*64 XCD swizzle
  const int sp = logical >> 5;          // 0..15 (2 splits per XCD = 4MB in L2)
  const int rb = logical & 31;          // 0..31
  const int row0 = rb * BM + wv * 64;   // this wave's 64 rows (4 tiles of 16)

  // 4 A-tiles fully K-resident: af[t][ks] = x[row0+t*16+c][ks*128+g*32 .. +32].
  i32x8 af[4][KS];
  #pragma unroll
  for (int t = 0; t < 4; ++t) {
    const char* xr = xn8 + (size_t)(row0 + t * 16 + c) * D + g * 32;
    #pragma unroll
    for (int ks = 0; ks < KS; ++ks) af[t][ks] = *(const i32x8*)(xr + ks * 128);
  }

  float accS[4][4];
  #pragma unroll
  for (int t = 0; t < 4; ++t)
    #pragma unroll
    for (int r = 0; r < 4; ++r) accS[t][r] = 0.0f;

  const f32x4 fzero = (f32x4)0.0f;    // persistent zero C-in for ks=0

  // Per-lane B base; chunk CN's fragment at CN*8192 + ks*2048 (+ lane*32).
  const char* gb = wt + (size_t)(sp * NCHUNK) * 8192 + lane * 32;

  i32x8 bA[KS], bB[KS];
  #pragma unroll
  for (int ks = 0; ks < KS; ++ks) bA[ks] = *(const i32x8*)(gb + ks * 2048);
  #pragma unroll
  for (int ks = 0; ks < KS; ++ks) bB[ks] = *(const i32x8*)(gb + 8192 + ks * 2048);

  f32x4 accP[4], accQ[4];

  // Prologue: chunk 0 (no exps) refill bA<-2; chunk 1, exps of 0, refill bB<-3.
  CHUNK_STEP(accP, accQ, bA, false, 2)
  CHUNK_STEP(accQ, accP, bB, true, 3)

  for (int ch = 2; ch + 1 < NCHUNK; ch += 2) {
    // chunk ch from bA -> accP, exps of accQ (ch-1); refill bA <- ch+2 (<=124).
    CHUNK_STEP(accP, accQ, bA, true, ch + 2)
    // chunk ch+1 from bB -> accQ, exps of accP (ch); refill bB <- ch+3 (clamped).
    CHUNK_STEP(accQ, accP, bB, true, (ch + 3 < NCHUNK ? ch + 3 : NCHUNK - 1))
  }
  // Last chunk 124 from bA (loaded during ch=122), exps of accQ (123).
  CHUNK_STEP(accP, accQ, bA, true, NCHUNK - 1)
  // Tail: exps of accP (chunk 124).
  #pragma unroll
  for (int t = 0; t < 4; ++t)
    #pragma unroll
    for (int r = 0; r < 4; ++r)
      accS[t][r] += __uint_as_float((unsigned)fmaf(accP[t][r], 8388608.0f, FEC));

  // Sum over the 16 col-lanes of each group; write per-(row,split) partials.
  #pragma unroll
  for (int t = 0; t < 4; ++t)
    #pragma unroll
    for (int r = 0; r < 4; ++r) {
      float S = accS[t][r];
      #pragma unroll
      for (int m = 1; m <= 8; m <<= 1) S += __shfl_xor(S, m, 64);
      if (c == 0)
        pS[(size_t)sp * N + row0 + t * 16 + g * 4 + r] = S;
    }
}
#undef CHUNK_STEP

// Merge: S over splits (scaled by e^-16); swap plain label term for f32 margin
// term; NLL mean.
__global__ void k_merge(const float* __restrict__ pS, const float* __restrict__ coslab,
                        float* __restrict__ out) {
  int row = blockIdx.x * 256 + threadIdx.x;
  float S = 0.0f;
  #pragma unroll
  for (int s = 0; s < NSPLIT; ++s) S += pS[(size_t)s * N + row];
  float cl = coslab[row];
  float zp = SCL * cl;
  float ccl = fminf(fmaxf(cl, -1.0f + EPSC), 1.0f - EPSC);
  float zm = SCL * (ccl * COSM - sqrtf(1.0f - ccl * ccl) * SINM);
  float denom = S * EM16 - __expf(zp - SCL) + __expf(zm - SCL);
  float nll = SCL + logf(denom) - zm;
  #pragma unroll
  for (int m = 1; m <= 32; m <<= 1) nll += __shfl_xor(nll, m, 64);
  __shared__ float part[4];
  if ((threadIdx.x & 63) == 0) part[threadIdx.x >> 6] = nll;
  __syncthreads();
  if (threadIdx.x == 0)
    atomicAdd(out, (part[0] + part[1] + part[2] + part[3]) * (1.0f / N));
}

extern "C" void kernel_launch(void* const* d_in, const int* in_sizes, int n_in,
                              void* d_out, int out_size, void* d_ws, size_t ws_size,
                              hipStream_t stream) {
  const float* x = (const float*)d_in[0];
  const float* w = (const float*)d_in[1];
  const int* labels = (const int*)d_in[2];
  float* out = (float*)d_out;

  // ws: xn8 fp8 [N*D] | wt fp8-grouped [C*D] | pS f32 [NSPLIT*N] | coslab f32 [N]
  char* xn8 = (char*)d_ws;
  char* wt = xn8 + (size_t)N * D;
  float* pS = (float*)(wt + (size_t)C * D);
  float* coslab = pS + (size_t)NSPLIT * N;

  hipLaunchKernelGGL(k_norm_x, dim3(N / 4), dim3(256), 0, stream, x, xn8, out);
  hipLaunchKernelGGL(k_normw_t, dim3(C / 16), dim3(256), 0, stream, w, wt);
  hipLaunchKernelGGL(k_lab, dim3(N / 4), dim3(256), 0, stream, x, w, labels, coslab);
  hipLaunchKernelGGL(k_fused, dim3(32 * NSPLIT), dim3(256), 0, stream, xn8, wt, pS);
  hipLaunchKernelGGL(k_merge, dim3(N / 256), dim3(256), 0, stream, pS, coslab, out);
}

// Round 15
// 124.070 us; speedup vs baseline: 1.7835x; 1.7835x over previous
//
#include <hip/hip_runtime.h>

// ArcMarginLoss fused: normalize -> MX-fp4 MFMA GEMM + fixed-max softmax -> NLL mean.
// N=8192, D=512, C=32000, scale=16, margin=0.2.
// R15 (= R14 with compile fix): mfma_scale op_sel args must be literal constants
// -> k-loop expanded via KS_STEP(0..3) macro. fp4 e2m1 + real per-32-block E8M0
// scales; 2 A-tiles/wave (~105 VGPR) -> 4 waves/SIMD; grid 1024 = 4 blocks/CU.
// Label/margin path exact f32. A/B share nibble order -> lane-permutes cancel.

typedef __attribute__((ext_vector_type(4))) float f32x4;
typedef __attribute__((ext_vector_type(4))) int i32x4;
typedef __attribute__((ext_vector_type(8))) int i32x8;

constexpr int N = 8192, D = 512, C = 32000;
constexpr int BM = 128;            // rows per block (4 waves x 2 tiles x 16 rows)
constexpr int NSPLIT = 16;         // column splits of C
constexpr int CPS = C / NSPLIT;    // 2000 cols per split
constexpr int NCHUNK = CPS / 16;   // 125 chunks of 16 cols
constexpr int KS = 4;              // 4 k-steps of K=128
constexpr float SCL = 16.0f;
constexpr float LOG2E = 1.4426950408889634f;
constexpr float S2 = SCL * LOG2E;              // 23.083 (folded into A pre-quant)
constexpr float COSM = 0.98006657784124163f;  // cos(0.2)
constexpr float SINM = 0.19866933079506122f;  // sin(0.2)
constexpr float EPSC = 1e-7f;
constexpr float EM16 = 1.12535174719259114e-07f;  // exp(-16)
constexpr float FEC = 1064871712.0f;  // Schraudolph zero-mean magic (validated R12)

// fp4 e2m1 magnitude grid {0,.5,1,1.5,2,3,4,6} at codes 0..7; piecewise-linear
// map grid->integers then round: m<2 -> 2m; m<4 -> m+2; else m/2+4.
__device__ __forceinline__ unsigned enc_fp4(float v, float inv) {
  unsigned s = (__float_as_uint(v) >> 31) << 3;
  float m = fabsf(v) * inv;
  float r = m < 2.0f ? 2.0f * m : (m < 4.0f ? m + 2.0f : fmaf(m, 0.5f, 4.0f));
  unsigned q = (unsigned)(r + 0.5f);
  return s | (q > 7u ? 7u : q);
}

// Per-32-block E8M0 scale from block absmax: smallest 2^e with absmax/2^e <= 6.
__device__ __forceinline__ void block_scale(float amax, unsigned& eB, float& inv) {
  unsigned u = __float_as_uint(amax * (1.0f / 6.0f));
  eB = (u >> 23) & 255u;
  if (u & 0x7fffffu) eB += 1u;      // ceil
  if (eB < 1u) eB = 1u;
  if (eB > 254u) eB = 254u;
  inv = __uint_as_float((254u - eB) << 23);  // 2^(127-eB)
}

__device__ __forceinline__ i32x8 up8(i32x4 v) {
  return __builtin_shufflevector(v, v, 0, 1, 2, 3, -1, -1, -1, -1);  // upper undef
}

// x: one wave per row. v = x_hat * S2; per-32-block scale; emit fp4 nibbles
// (row stride 256B) + scale bytes [row][g][ks] (16B/row). Zero-inits out scalar.
__global__ void k_norm_x(const float* __restrict__ in, unsigned* __restrict__ xn4,
                         unsigned char* __restrict__ xsc, float* __restrict__ outz) {
  if (blockIdx.x == 0 && threadIdx.x == 0) *outz = 0.0f;
  int w = (blockIdx.x << 2) + (threadIdx.x >> 6);
  int L = threadIdx.x & 63;
  const float* row = in + (size_t)w * D;
  float f[8];
  *(f32x4*)&f[0] = *(const f32x4*)(row + L * 8);
  *(f32x4*)&f[4] = *(const f32x4*)(row + L * 8 + 4);
  float ss = 0.f;
  #pragma unroll
  for (int i = 0; i < 8; ++i) ss += f[i] * f[i];
  #pragma unroll
  for (int m = 1; m <= 32; m <<= 1) ss += __shfl_xor(ss, m, 64);
  float sc = S2 / fmaxf(sqrtf(ss), 1e-12f);
  float v[8], am = 0.f;
  #pragma unroll
  for (int i = 0; i < 8; ++i) { v[i] = f[i] * sc; am = fmaxf(am, fabsf(v[i])); }
  am = fmaxf(am, __shfl_xor(am, 1, 64));
  am = fmaxf(am, __shfl_xor(am, 2, 64));   // quad (= one 32-elem block) absmax
  unsigned eB; float inv;
  block_scale(am, eB, inv);
  unsigned pk = 0;
  #pragma unroll
  for (int j = 0; j < 8; ++j) pk |= enc_fp4(v[j], inv) << (4 * j);
  xn4[(size_t)w * 64 + L] = pk;
  if ((L & 3) == 0) {
    int kb = L >> 2;  // block index; stored at [row][g=kb&3][ks=kb>>2]
    xsc[(size_t)w * 16 + (kb & 3) * 4 + (kb >> 2)] = (unsigned char)eB;
  }
}

// w: one block per 16-col group. Quantize to fp4 with per-32-block scales; emit
// chunk image (4KB: addr = ks*1024 + (g*16+col)*16 + j/2, lane-contiguous for the
// fused per-lane 16B read) + 256B scale image [col][g][ks].
__global__ void k_normw_t(const float* __restrict__ in, unsigned char* __restrict__ wt4,
                          unsigned char* __restrict__ wsc) {
  __shared__ unsigned lbuf[1024];         // 4KB chunk image
  __shared__ unsigned char sbuf[256];     // scale image
  const int tid = threadIdx.x, wv = tid >> 6, L = tid & 63;
  const int gidx = blockIdx.x;
  #pragma unroll
  for (int t = 0; t < 4; ++t) {
    int rl = t * 4 + wv;  // 0..15 (col within group)
    const float* row = in + ((size_t)gidx * 16 + rl) * D;
    float f[8];
    *(f32x4*)&f[0] = *(const f32x4*)(row + L * 8);
    *(f32x4*)&f[4] = *(const f32x4*)(row + L * 8 + 4);
    float ss = 0.f;
    #pragma unroll
    for (int i = 0; i < 8; ++i) ss += f[i] * f[i];
    #pragma unroll
    for (int m = 1; m <= 32; m <<= 1) ss += __shfl_xor(ss, m, 64);
    float sc = 1.0f / fmaxf(sqrtf(ss), 1e-12f);
    float v[8], am = 0.f;
    #pragma unroll
    for (int i = 0; i < 8; ++i) { v[i] = f[i] * sc; am = fmaxf(am, fabsf(v[i])); }
    am = fmaxf(am, __shfl_xor(am, 1, 64));
    am = fmaxf(am, __shfl_xor(am, 2, 64));
    unsigned eB; float inv;
    block_scale(am, eB, inv);
    unsigned pk = 0;
    #pragma unroll
    for (int j = 0; j < 8; ++j) pk |= enc_fp4(v[j], inv) << (4 * j);
    // lane L covers k=8L..8L+8: ks=L>>4, g=(L>>2)&3, dword slot (L&3)
    lbuf[(L >> 4) * 256 + (((L >> 2) & 3) * 16 + rl) * 4 + (L & 3)] = pk;
    if ((L & 3) == 0)
      sbuf[rl * 16 + ((L >> 2) & 3) * 4 + (L >> 4)] = (unsigned char)eB;
  }
  __syncthreads();
  uint4* dst = (uint4*)(wt4 + (size_t)gidx * 4096);
  dst[tid] = ((const uint4*)lbuf)[tid];
  if (tid < 64)
    ((unsigned*)(wsc + (size_t)gidx * 256))[tid] = ((const unsigned*)sbuf)[tid];
}

// Label-column cosine in f32 (one wave per row) -> coslab[N].
__global__ void k_lab(const float* __restrict__ x, const float* __restrict__ w,
                      const int* __restrict__ labels, float* __restrict__ coslab) {
  int r = (blockIdx.x << 2) + (threadIdx.x >> 6);
  int lane = threadIdx.x & 63;
  const float* xr = x + (size_t)r * D;
  const float* wr = w + (size_t)labels[r] * D;
  f32x4 a = *(const f32x4*)(xr + lane * 8);
  f32x4 b = *(const f32x4*)(xr + lane * 8 + 4);
  f32x4 p = *(const f32x4*)(wr + lane * 8);
  f32x4 q = *(const f32x4*)(wr + lane * 8 + 4);
  float xx = a.x*a.x + a.y*a.y + a.z*a.z + a.w*a.w + b.x*b.x + b.y*b.y + b.z*b.z + b.w*b.w;
  float ww = p.x*p.x + p.y*p.y + p.z*p.z + p.w*p.w + q.x*q.x + q.y*q.y + q.z*q.z + q.w*q.w;
  float xw = a.x*p.x + a.y*p.y + a.z*p.z + a.w*p.w + b.x*q.x + b.y*q.y + b.z*q.z + b.w*q.w;
  #pragma unroll
  for (int m = 1; m <= 32; m <<= 1) {
    xx += __shfl_xor(xx, m, 64);
    ww += __shfl_xor(ww, m, 64);
    xw += __shfl_xor(xw, m, 64);
  }
  if (lane == 0)
    coslab[r] = xw / (fmaxf(sqrtf(xx), 1e-12f) * fmaxf(sqrtf(ww), 1e-12f));
}

// One k-step with LITERAL ks (op_sel must be an immediate). ks=0 seeds fzero.
// DOEXP_ODD interleaves the fast-exp2 of ACCPREV tile TT; then staggered refill.
#define KS_STEP(KSL, ACC, ACCPREV, DOEXP_ODD, TT, CHNEXT)                     \
    __builtin_amdgcn_s_setprio(1);                                            \
    ACC[0] = __builtin_amdgcn_mfma_scale_f32_16x16x128_f8f6f4(                \
        up8(af4[0][KSL]), up8(b4[KSL]), (KSL) == 0 ? fzero : ACC[0],          \
        4, 4, KSL, asc0, KSL, bsc);                                           \
    ACC[1] = __builtin_amdgcn_mfma_scale_f32_16x16x128_f8f6f4(                \
        up8(af4[1][KSL]), up8(b4[KSL]), (KSL) == 0 ? fzero : ACC[1],          \
        4, 4, KSL, asc1, KSL, bsc);                                           \
    __builtin_amdgcn_s_setprio(0);                                            \
    if (DOEXP_ODD) {                                                          \
      _Pragma("unroll")                                                       \
      for (int r = 0; r < 4; ++r)                                             \
        accS[TT][r] += __uint_as_float(                                       \
            (unsigned)fmaf(ACCPREV[TT][r], 8388608.0f, FEC));                 \
    }                                                                         \
    b4[KSL] = *(const i32x4*)(gb + (size_t)(CHNEXT) * 4096 + (KSL) * 1024);

#define CHUNK_STEP(ACC, ACCPREV, DOEXP, CHNEXT)                               \
  {                                                                           \
    int nsc = *(const int*)(gsc + (size_t)(CHNEXT) * 256);                    \
    KS_STEP(0, ACC, ACCPREV, false, 0, CHNEXT)                                \
    KS_STEP(1, ACC, ACCPREV, DOEXP, 0, CHNEXT)                                \
    KS_STEP(2, ACC, ACCPREV, false, 0, CHNEXT)                                \
    KS_STEP(3, ACC, ACCPREV, DOEXP, 1, CHNEXT)                                \
    bsc = nsc;                                                                \
  }

// Fused MX-fp4 GEMM, barrier-free, 4 waves/SIMD, acc ping-pong.
__global__ __launch_bounds__(256, 4) void k_fused(
    const unsigned char* __restrict__ xn4, const unsigned char* __restrict__ xsc,
    const unsigned char* __restrict__ wt4, const unsigned char* __restrict__ wsc,
    float* __restrict__ pS) {
  const int tid = threadIdx.x;
  const int wv = tid >> 6, lane = tid & 63;
  const int g = lane >> 4, c = lane & 15;
  const int bid = blockIdx.x;
  const int logical = (bid & 7) * 128 + (bid >> 3);  // 1024 = 8*128 XCD swizzle
  const int sp = logical >> 6;          // 0..15 (2 splits per XCD)
  const int rb = logical & 63;          // 0..63
  const int row0 = rb * BM + wv * 32;   // this wave's 32 rows (2 tiles of 16)

  // 2 A-tiles fully K-resident as fp4: af4[t][ks] = 16B at row*256 + ks*64 + g*16.
  i32x4 af4[2][KS];
  int asc0, asc1;
  {
    const unsigned char* x0 = xn4 + (size_t)(row0 + c) * 256 + g * 16;
    const unsigned char* x1 = xn4 + (size_t)(row0 + 16 + c) * 256 + g * 16;
    #pragma unroll
    for (int ks = 0; ks < KS; ++ks) {
      af4[0][ks] = *(const i32x4*)(x0 + ks * 64);
      af4[1][ks] = *(const i32x4*)(x1 + ks * 64);
    }
    asc0 = *(const int*)(xsc + (size_t)(row0 + c) * 16 + g * 4);
    asc1 = *(const int*)(xsc + (size_t)(row0 + 16 + c) * 16 + g * 4);
  }

  float accS[2][4];
  #pragma unroll
  for (int t = 0; t < 2; ++t)
    #pragma unroll
    for (int r = 0; r < 4; ++r) accS[t][r] = 0.0f;

  const f32x4 fzero = (f32x4)0.0f;

  const unsigned char* gb = wt4 + (size_t)(sp * NCHUNK) * 4096 + lane * 16;
  const unsigned char* gsc = wsc + (size_t)(sp * NCHUNK) * 256 + c * 16 + g * 4;

  i32x4 b4[KS];
  #pragma unroll
  for (int ks = 0; ks < KS; ++ks) b4[ks] = *(const i32x4*)(gb + ks * 1024);
  int bsc = *(const int*)gsc;

  f32x4 accP[2], accQ[2];

  // Prologue: chunk 0 -> accP (no exps); prefetch chunk 1.
  CHUNK_STEP(accP, accQ, false, 1)

  for (int ch = 1; ch + 1 < NCHUNK; ch += 2) {
    CHUNK_STEP(accQ, accP, true, ch + 1)
    CHUNK_STEP(accP, accQ, true, (ch + 2 < NCHUNK ? ch + 2 : NCHUNK - 1))
  }
  // Tail: exps of accP (chunk 124).
  #pragma unroll
  for (int t = 0; t < 2; ++t)
    #pragma unroll
    for (int r = 0; r < 4; ++r)
      accS[t][r] += __uint_as_float((unsigned)fmaf(accP[t][r], 8388608.0f, FEC));

  // Sum over the 16 col-lanes of each group; write per-(row,split) partials.
  #pragma unroll
  for (int t = 0; t < 2; ++t)
    #pragma unroll
    for (int r = 0; r < 4; ++r) {
      float S = accS[t][r];
      #pragma unroll
      for (int m = 1; m <= 8; m <<= 1) S += __shfl_xor(S, m, 64);
      if (c == 0)
        pS[(size_t)sp * N + row0 + t * 16 + g * 4 + r] = S;
    }
}
#undef CHUNK_STEP
#undef KS_STEP

// Merge: S over splits (x e^-16); swap plain label term for f32 margin term; mean.
__global__ void k_merge(const float* __restrict__ pS, const float* __restrict__ coslab,
                        float* __restrict__ out) {
  int row = blockIdx.x * 256 + threadIdx.x;
  float S = 0.0f;
  #pragma unroll
  for (int s = 0; s < NSPLIT; ++s) S += pS[(size_t)s * N + row];
  float cl = coslab[row];
  float zp = SCL * cl;
  float ccl = fminf(fmaxf(cl, -1.0f + EPSC), 1.0f - EPSC);
  float zm = SCL * (ccl * COSM - sqrtf(1.0f - ccl * ccl) * SINM);
  float denom = S * EM16 - __expf(zp - SCL) + __expf(zm - SCL);
  float nll = SCL + logf(denom) - zm;
  #pragma unroll
  for (int m = 1; m <= 32; m <<= 1) nll += __shfl_xor(nll, m, 64);
  __shared__ float part[4];
  if ((threadIdx.x & 63) == 0) part[threadIdx.x >> 6] = nll;
  __syncthreads();
  if (threadIdx.x == 0)
    atomicAdd(out, (part[0] + part[1] + part[2] + part[3]) * (1.0f / N));
}

extern "C" void kernel_launch(void* const* d_in, const int* in_sizes, int n_in,
                              void* d_out, int out_size, void* d_ws, size_t ws_size,
                              hipStream_t stream) {
  const float* x = (const float*)d_in[0];
  const float* w = (const float*)d_in[1];
  const int* labels = (const int*)d_in[2];
  float* out = (float*)d_out;

  // ws: xn4 fp4 [N*256B] | xsc [N*16B] | wt4 fp4 [2000*4KB] | wsc [2000*256B]
  //   | pS f32 [NSPLIT*N] | coslab f32 [N]
  unsigned char* xn4 = (unsigned char*)d_ws;
  unsigned char* xsc = xn4 + (size_t)N * 256;
  unsigned char* wt4 = xsc + (size_t)N * 16;
  unsigned char* wsc = wt4 + (size_t)2000 * 4096;
  float* pS = (float*)(wsc + (size_t)2000 * 256);
  float* coslab = pS + (size_t)NSPLIT * N;

  hipLaunchKernelGGL(k_norm_x, dim3(N / 4), dim3(256), 0, stream,
                     x, (unsigned*)xn4, xsc, out);
  hipLaunchKernelGGL(k_normw_t, dim3(C / 16), dim3(256), 0, stream, w, wt4, wsc);
  hipLaunchKernelGGL(k_lab, dim3(N / 4), dim3(256), 0, stream, x, w, labels, coslab);
  hipLaunchKernelGGL(k_fused, dim3(64 * NSPLIT), dim3(256), 0, stream,
                     xn4, xsc, wt4, wsc, pS);
  hipLaunchKernelGGL(k_merge, dim3(N / 256), dim3(256), 0, stream, pS, coslab, out);
}